// Round 5
// baseline (488.147 us; speedup 1.0000x reference)
//
#include <hip/hip_runtime.h>

typedef __attribute__((ext_vector_type(8))) __bf16 bf16x8;
typedef __attribute__((ext_vector_type(4))) float f32x4;

#define B_ROWS 16384
#define N_HALF 8192
#define D_DIM  2048
#define H_DIM  2048
#define F_DIM  128

static constexpr float kInvT = 14.285714285714286f;  // 1/0.07
static constexpr float kS2   = 20.60992915555662f;   // (1/0.07)*log2(e)

// async global->LDS, 16B per lane. LDS dest is wave-uniform base; HW adds lane*16.
__device__ __forceinline__ void async16(void* lds, const void* g) {
  __builtin_amdgcn_global_load_lds((const __attribute__((address_space(1))) void*)g,
                                   (__attribute__((address_space(3))) void*)lds,
                                   16, 0, 0);
}

// ---------------- f32 -> bf16 convert, 8 elems/thread ----------------
__global__ void cvt_bf16_kernel(const float* __restrict__ in, __bf16* __restrict__ out, int n) {
  int i = (blockIdx.x * blockDim.x + threadIdx.x) * 8;
  if (i >= n) return;
  float4 a = *(const float4*)(in + i);
  float4 b = *(const float4*)(in + i + 4);
  bf16x8 o;
  o[0] = (__bf16)a.x; o[1] = (__bf16)a.y; o[2] = (__bf16)a.z; o[3] = (__bf16)a.w;
  o[4] = (__bf16)b.x; o[5] = (__bf16)b.y; o[6] = (__bf16)b.z; o[7] = (__bf16)b.w;
  *(bf16x8*)(out + i) = o;
}

// ---------------- transpose + cvt: out[c][r] = in[r][c], block (32,8) ----------------
__global__ void transpose_cvt_kernel(const float* __restrict__ in, __bf16* __restrict__ out,
                                     int R, int C) {
  __shared__ float tile[32][33];
  int tx = threadIdx.x, ty = threadIdx.y;
  int c0 = blockIdx.x * 32, r0 = blockIdx.y * 32;
  for (int i = 0; i < 4; i++)
    tile[ty + i * 8][tx] = in[(size_t)(r0 + ty + i * 8) * C + c0 + tx];
  __syncthreads();
  for (int i = 0; i < 4; i++)
    out[(size_t)(c0 + ty + i * 8) * R + r0 + tx] = (__bf16)tile[tx][ty + i * 8];
}

// ---------------- GEMM1: 256x256 8-phase counted-vmcnt schedule ----------------
#define BM 256
#define BK 64
#define NT_K (D_DIM / BK)

__global__ __launch_bounds__(512, 2) void gemm1_8ph_kernel(
    const __bf16* __restrict__ A, const __bf16* __restrict__ BT,
    const float* __restrict__ bias, __bf16* __restrict__ C) {
  __shared__ __align__(16) __bf16 As[2][BM * BK];
  __shared__ __align__(16) __bf16 Bs[2][BM * BK];
  const int t = threadIdx.x;
  const int wave = t >> 6, lane = t & 63;
  const int l15 = lane & 15, quad = lane >> 4, l7 = l15 & 7;
  const int wy = wave & 1, wx = wave >> 1;  // 2M x 4N

  // XCD-bijective swizzle: 512 blocks, 8 XCDs, 64 per XCD.
  const int wg = ((int)blockIdx.x & 7) * 64 + ((int)blockIdx.x >> 3);
  const int n0 = (wg & 7) * 256;
  const int m0 = (wg >> 3) * 256;

  const int tr = t >> 3;
  const int csw = ((t & 7) ^ (tr & 7)) * 8;
  const __bf16* pA = A + (size_t)(m0 + tr) * D_DIM + csw;
  const __bf16* pB = BT + (size_t)(n0 + tr) * D_DIM + csw;
  const int ldsw = wave * 512;

  auto stageA = [&](int buf, int h, int kk) {
    async16(&As[buf][h * 8192 + ldsw], pA + (size_t)(h * 128) * D_DIM + kk);
    async16(&As[buf][h * 8192 + 4096 + ldsw], pA + (size_t)(h * 128 + 64) * D_DIM + kk);
  };
  auto stageB = [&](int buf, int h, int kk) {
    async16(&Bs[buf][h * 8192 + ldsw], pB + (size_t)(h * 128) * D_DIM + kk);
    async16(&Bs[buf][h * 8192 + 4096 + ldsw], pB + (size_t)(h * 128 + 64) * D_DIM + kk);
  };

  const int arow = wy * 16 + l15;
  const int brow = wx * 16 + l15;
  const int s0 = (quad ^ l7) * 8;
  const int s1 = ((4 + quad) ^ l7) * 8;

  f32x4 acc[8][4];
#pragma unroll
  for (int f = 0; f < 8; f++)
#pragma unroll
    for (int n = 0; n < 4; n++) acc[f][n] = 0.f;

  // prologue: t0.B, t0.A, t1.B (12 loads); wait until t0 fully landed.
  stageB(0, 0, 0); stageB(0, 1, 0);
  stageA(0, 0, 0); stageA(0, 1, 0);
  stageB(1, 0, BK); stageB(1, 1, BK);
  asm volatile("s_waitcnt vmcnt(4)" ::: "memory");
  __builtin_amdgcn_s_barrier();

  for (int tk = 0; tk < NT_K; ++tk) {
    const int cur = tk & 1, nxt = cur ^ 1;
    const __bf16* Ac = &As[cur][0];
    const __bf16* Bc = &Bs[cur][0];
#define LDA(f, s) (*(const bf16x8*)(Ac + ((f) * 32 + arow) * 64 + (s)))
#define LDB(n, s) (*(const bf16x8*)(Bc + ((n) * 64 + brow) * 64 + (s)))
    bf16x8 b0[4], b1[4];
    // ---- ph1: lo-frags x ks0 ; stage (t+1).Ah0 -> nxt ----
    {
      bf16x8 a0 = LDA(0, s0), a1 = LDA(1, s0), a2 = LDA(2, s0), a3 = LDA(3, s0);
      b0[0] = LDB(0, s0); b0[1] = LDB(1, s0); b0[2] = LDB(2, s0); b0[3] = LDB(3, s0);
      if (tk + 1 < NT_K) stageA(nxt, 0, (tk + 1) * BK);
      __builtin_amdgcn_s_barrier();
      asm volatile("s_waitcnt lgkmcnt(0)" ::: "memory");
      __builtin_amdgcn_s_setprio(1);
#pragma unroll
      for (int n = 0; n < 4; n++) {
        acc[0][n] = __builtin_amdgcn_mfma_f32_16x16x32_bf16(a0, b0[n], acc[0][n], 0, 0, 0);
        acc[1][n] = __builtin_amdgcn_mfma_f32_16x16x32_bf16(a1, b0[n], acc[1][n], 0, 0, 0);
        acc[2][n] = __builtin_amdgcn_mfma_f32_16x16x32_bf16(a2, b0[n], acc[2][n], 0, 0, 0);
        acc[3][n] = __builtin_amdgcn_mfma_f32_16x16x32_bf16(a3, b0[n], acc[3][n], 0, 0, 0);
      }
      __builtin_amdgcn_s_setprio(0);
      __builtin_amdgcn_s_barrier();
    }
    // ---- ph2: hi-frags x ks0 ; stage (t+1).Ah1 -> nxt ----
    {
      bf16x8 a4 = LDA(4, s0), a5 = LDA(5, s0), a6 = LDA(6, s0), a7 = LDA(7, s0);
      if (tk + 1 < NT_K) stageA(nxt, 1, (tk + 1) * BK);
      __builtin_amdgcn_s_barrier();
      asm volatile("s_waitcnt lgkmcnt(0)" ::: "memory");
      __builtin_amdgcn_s_setprio(1);
#pragma unroll
      for (int n = 0; n < 4; n++) {
        acc[4][n] = __builtin_amdgcn_mfma_f32_16x16x32_bf16(a4, b0[n], acc[4][n], 0, 0, 0);
        acc[5][n] = __builtin_amdgcn_mfma_f32_16x16x32_bf16(a5, b0[n], acc[5][n], 0, 0, 0);
        acc[6][n] = __builtin_amdgcn_mfma_f32_16x16x32_bf16(a6, b0[n], acc[6][n], 0, 0, 0);
        acc[7][n] = __builtin_amdgcn_mfma_f32_16x16x32_bf16(a7, b0[n], acc[7][n], 0, 0, 0);
      }
      __builtin_amdgcn_s_setprio(0);
      __builtin_amdgcn_s_barrier();
    }
    // ---- ph3: lo-frags x ks1 ; no stage ----
    {
      bf16x8 a0 = LDA(0, s1), a1 = LDA(1, s1), a2 = LDA(2, s1), a3 = LDA(3, s1);
      b1[0] = LDB(0, s1); b1[1] = LDB(1, s1); b1[2] = LDB(2, s1); b1[3] = LDB(3, s1);
      __builtin_amdgcn_s_barrier();
      asm volatile("s_waitcnt lgkmcnt(0)" ::: "memory");
      __builtin_amdgcn_s_setprio(1);
#pragma unroll
      for (int n = 0; n < 4; n++) {
        acc[0][n] = __builtin_amdgcn_mfma_f32_16x16x32_bf16(a0, b1[n], acc[0][n], 0, 0, 0);
        acc[1][n] = __builtin_amdgcn_mfma_f32_16x16x32_bf16(a1, b1[n], acc[1][n], 0, 0, 0);
        acc[2][n] = __builtin_amdgcn_mfma_f32_16x16x32_bf16(a2, b1[n], acc[2][n], 0, 0, 0);
        acc[3][n] = __builtin_amdgcn_mfma_f32_16x16x32_bf16(a3, b1[n], acc[3][n], 0, 0, 0);
      }
      __builtin_amdgcn_s_setprio(0);
      __builtin_amdgcn_s_barrier();
    }
    // ---- ph4: hi-frags x ks1 ; stage (t+2).B -> cur ; vmcnt ----
    {
      bf16x8 a4 = LDA(4, s1), a5 = LDA(5, s1), a6 = LDA(6, s1), a7 = LDA(7, s1);
      if (tk + 2 < NT_K) {
        stageB(cur, 0, (tk + 2) * BK);
        stageB(cur, 1, (tk + 2) * BK);
        asm volatile("s_waitcnt vmcnt(4)" ::: "memory");
      } else if (tk + 1 < NT_K) {
        asm volatile("s_waitcnt vmcnt(0)" ::: "memory");
      }
      __builtin_amdgcn_s_barrier();
      asm volatile("s_waitcnt lgkmcnt(0)" ::: "memory");
      __builtin_amdgcn_s_setprio(1);
#pragma unroll
      for (int n = 0; n < 4; n++) {
        acc[4][n] = __builtin_amdgcn_mfma_f32_16x16x32_bf16(a4, b1[n], acc[4][n], 0, 0, 0);
        acc[5][n] = __builtin_amdgcn_mfma_f32_16x16x32_bf16(a5, b1[n], acc[5][n], 0, 0, 0);
        acc[6][n] = __builtin_amdgcn_mfma_f32_16x16x32_bf16(a6, b1[n], acc[6][n], 0, 0, 0);
        acc[7][n] = __builtin_amdgcn_mfma_f32_16x16x32_bf16(a7, b1[n], acc[7][n], 0, 0, 0);
      }
      __builtin_amdgcn_s_setprio(0);
      __builtin_amdgcn_s_barrier();
    }
#undef LDA
#undef LDB
  }

  // epilogue: bias + relu, bf16 store
#pragma unroll
  for (int n = 0; n < 4; n++) {
    int col = n0 + n * 64 + wx * 16 + l15;
    float bv = bias[col];
#pragma unroll
    for (int f = 0; f < 8; f++) {
      int rowb = m0 + f * 32 + wy * 16 + quad * 4;
#pragma unroll
      for (int r = 0; r < 4; r++) {
        float v = fmaxf(acc[f][n][r] + bv, 0.f);
        C[(size_t)(rowb + r) * H_DIM + col] = (__bf16)v;
      }
    }
  }
}

// ---------------- fused GEMM2 + bias + L2-normalize: z = norm(A @ BT^T + b2) ----------------
__global__ __launch_bounds__(256) void proj_norm_kernel(
    const __bf16* __restrict__ A, const __bf16* __restrict__ BT,
    const float* __restrict__ bias, float* __restrict__ zf, __bf16* __restrict__ zb, int K) {
  __shared__ __align__(16) __bf16 As[64 * 32];
  __shared__ __align__(16) __bf16 Bs[128 * 32];
  __shared__ float pbuf[64 * 128];
  const int t = threadIdx.x;
  const int wave = t >> 6, lane = t & 63;
  const int l15 = lane & 15, quad = lane >> 4;
  const int wy = wave >> 1, wx = wave & 1;
  const int m0 = blockIdx.x * 64;
  const int sr = t >> 2;
  const int sk = (((t & 3) ^ ((sr >> 1) & 3))) * 8;
  const int sw = (l15 >> 1) & 3;

  f32x4 acc[2][4];
  for (int i = 0; i < 2; i++)
    for (int j = 0; j < 4; j++) acc[i][j] = 0.f;

  for (int k0 = 0; k0 < K; k0 += 32) {
    async16(As + wave * 512, A + (size_t)(m0 + sr) * K + k0 + sk);
    async16(Bs + 0 * 2048 + wave * 512, BT + (size_t)(0  + sr) * K + k0 + sk);
    async16(Bs + 1 * 2048 + wave * 512, BT + (size_t)(64 + sr) * K + k0 + sk);
    __syncthreads();
    bf16x8 af[2], bfr[4];
    for (int i = 0; i < 2; i++)
      af[i] = *(const bf16x8*)(As + (wy * 32 + i * 16 + l15) * 32 + (quad ^ sw) * 8);
    for (int i = 0; i < 4; i++)
      bfr[i] = *(const bf16x8*)(Bs + (wx * 64 + i * 16 + l15) * 32 + (quad ^ sw) * 8);
    for (int mi = 0; mi < 2; mi++)
      for (int ni = 0; ni < 4; ni++)
        acc[mi][ni] = __builtin_amdgcn_mfma_f32_16x16x32_bf16(af[mi], bfr[ni], acc[mi][ni], 0, 0, 0);
    __syncthreads();
  }
  // epilogue: p + bias into LDS
  for (int ni = 0; ni < 4; ni++) {
    int col = wx * 64 + ni * 16 + l15;
    float bv = bias[col];
    for (int mi = 0; mi < 2; mi++) {
      int lrow = wy * 32 + mi * 16 + quad * 4;
      for (int r = 0; r < 4; r++)
        pbuf[(lrow + r) * 128 + col] = acc[mi][ni][r] + bv;
    }
  }
  __syncthreads();
  // normalize: wave handles rows [wave*16, wave*16+16)
  for (int it = 0; it < 16; it++) {
    int lrow = wave * 16 + it;
    float v0 = pbuf[lrow * 128 + lane];
    float v1 = pbuf[lrow * 128 + 64 + lane];
    float ss = v0 * v0 + v1 * v1;
    for (int m = 1; m < 64; m <<= 1) ss += __shfl_xor(ss, m);
    float inv = 1.f / fmaxf(sqrtf(ss), 1e-12f);
    float z0 = v0 * inv, z1 = v1 * inv;
    size_t base = (size_t)(m0 + lrow) * F_DIM;
    zf[base + lane] = z0;
    zf[base + 64 + lane] = z1;
    zb[base + lane] = (__bf16)z0;
    zb[base + 64 + lane] = (__bf16)z1;
  }
}

// ---------------- sim + row-sum of exp, SYMMETRIC upper-triangle version ----------------
// Off-diagonal tile (rt,ct), ct>rt, computed once; exp terms credit rows via a
// register accumulator (atomic-flushed only on rt change, <=2/block) and credit
// COLUMNS via NON-ATOMIC partial-sum stores to colpart[(ct*128+rt)*2+wy][128]
// (R4: the per-tile column atomicAdds serialized in L2 and stalled every
// tile's barrier-vmcnt drain -- that was R3's mask). col_reduce_kernel folds
// the partials into S afterwards.
__global__ __launch_bounds__(256) void sim_lse_tri_kernel(const __bf16* __restrict__ zb,
                                                          float* __restrict__ S,
                                                          float* __restrict__ colpart) {
  __shared__ __align__(16) __bf16 Bs[128 * 128];
  const int t = threadIdx.x;
  const int wave = t >> 6, lane = t & 63;
  const int l15 = lane & 15, quad = lane >> 4;
  const int wy = wave >> 1, wx = wave & 1;
  const int srow = t >> 4;
  const int schunk = (t & 15) ^ srow;

  // decode first tile index: u -> (rt, ct), f(r) = 128r - r(r-1)/2
  const int u = blockIdx.x * 8;
  auto fr = [](int r) { return r * 128 - (r * (r - 1)) / 2; };
  int rt = (int)(128.5f - sqrtf(16512.25f - 2.0f * (float)u));
  while (fr(rt + 1) <= u) rt++;
  while (fr(rt) > u) rt--;
  int ct = rt + (u - fr(rt));

  bf16x8 a[4][4];
  float rowacc[4][4];
  auto load_a = [&](int rtile) {
#pragma unroll
    for (int mi = 0; mi < 4; mi++)
#pragma unroll
      for (int ks = 0; ks < 4; ks++)
        a[mi][ks] = *(const bf16x8*)(zb + (size_t)(rtile * 128 + wy * 64 + mi * 16 + l15) * 128 +
                                     ks * 32 + quad * 8);
  };
  auto flush_rows = [&](int rtile) {
#pragma unroll
    for (int mi = 0; mi < 4; mi++)
#pragma unroll
      for (int r = 0; r < 4; r++) {
        float v = rowacc[mi][r];
        v += __shfl_xor(v, 1);
        v += __shfl_xor(v, 2);
        v += __shfl_xor(v, 4);
        v += __shfl_xor(v, 8);
        if (l15 == 0)
          atomicAdd(&S[rtile * 128 + wy * 64 + mi * 16 + quad * 4 + r], v);
        rowacc[mi][r] = 0.f;
      }
  };

#pragma unroll
  for (int mi = 0; mi < 4; mi++)
#pragma unroll
    for (int r = 0; r < 4; r++) rowacc[mi][r] = 0.f;
  load_a(rt);

  for (int it = 0; it < 8; ++it) {
    // stage B tile (rows ct*128..+128 of zb), 16-chunk XOR swizzle
    const __bf16* gbase = zb + (size_t)(ct * 128) * 128;
#pragma unroll
    for (int q = 0; q < 8; q++)
      async16(Bs + q * 2048 + wave * 512, gbase + (size_t)(q * 16 + srow) * 128 + schunk * 8);
    __syncthreads();
    const bool diag = (ct == rt);  // block-uniform
#pragma unroll
    for (int ni = 0; ni < 4; ni++) {
      bf16x8 b[4];
      const int brow = wx * 64 + ni * 16 + l15;
#pragma unroll
      for (int ks = 0; ks < 4; ks++)
        b[ks] = *(const bf16x8*)(Bs + brow * 128 + (((ks * 4 + quad) ^ l15) * 8));
      float colsum = 0.f;
      if (diag) {
#pragma unroll
        for (int mi = 0; mi < 4; mi++) {
          f32x4 acc = 0.f;
#pragma unroll
          for (int ks = 0; ks < 4; ks++)
            acc = __builtin_amdgcn_mfma_f32_16x16x32_bf16(a[mi][ks], b[ks], acc, 0, 0, 0);
          const int lrb = wy * 64 + mi * 16 + quad * 4;
#pragma unroll
          for (int r = 0; r < 4; r++) {
            float term = __builtin_amdgcn_exp2f(fmaf(acc[r], kS2, -kS2));
            rowacc[mi][r] += (lrb + r == brow) ? 0.f : term;
          }
        }
      } else {
#pragma unroll
        for (int mi = 0; mi < 4; mi++) {
          f32x4 acc = 0.f;
#pragma unroll
          for (int ks = 0; ks < 4; ks++)
            acc = __builtin_amdgcn_mfma_f32_16x16x32_bf16(a[mi][ks], b[ks], acc, 0, 0, 0);
#pragma unroll
          for (int r = 0; r < 4; r++) {
            float term = __builtin_amdgcn_exp2f(fmaf(acc[r], kS2, -kS2));
            rowacc[mi][r] += term;
            colsum += term;
          }
        }
        // column partials: reduce over quads, then plain store (no atomics)
        colsum += __shfl_xor(colsum, 16);
        colsum += __shfl_xor(colsum, 32);
        if (quad == 0)
          colpart[((size_t)(ct * 128 + rt) * 2 + wy) * 128 + brow] = colsum;
      }
    }
    __syncthreads();
    if (it < 7) {
      ct++;
      if (ct == 128) {
        flush_rows(rt);
        rt++;
        ct = rt;
        load_a(rt);
      }
    }
  }
  flush_rows(rt);
}

// ---------------- fold column partials into S ----------------
// grid (4 rt-chunks, 128 ct), 128 threads (one per col). <=4 atomics/address.
__global__ __launch_bounds__(128) void col_reduce_kernel(const float* __restrict__ colpart,
                                                         float* __restrict__ S) {
  const int ct = blockIdx.y;
  const int r0 = blockIdx.x * 32;
  if (r0 >= ct) return;
  const int t = threadIdx.x;
  const int rend = min(ct, r0 + 32);
  float s = 0.f;
  for (int rt = r0; rt < rend; rt++) {
    const float* p = colpart + (size_t)(ct * 128 + rt) * 2 * 128;
    s += p[t] + p[128 + t];
  }
  atomicAdd(&S[ct * 128 + t], s);
}

// ---------------- pos + loss reduction ----------------
__global__ void loss_kernel(const float* __restrict__ zf, const float* __restrict__ S,
                            float* __restrict__ out) {
  int wave = threadIdx.x >> 6, lane = threadIdx.x & 63;
  int base = blockIdx.x * 64 + wave * 16;
  float local = 0.f;
  for (int it = 0; it < 16; it++) {
    int row = base + it;
    int j = (row + N_HALF) & (B_ROWS - 1);
    const float* za = zf + (size_t)row * F_DIM;
    const float* zc = zf + (size_t)j * F_DIM;
    float d = za[lane] * zc[lane] + za[lane + 64] * zc[lane + 64];
    for (int m = 1; m < 64; m <<= 1) d += __shfl_xor(d, m);
    float pos = d * kInvT;
    float lse = logf(S[row]) + kInvT;
    local += (lse - pos);
  }
  if (lane == 0) atomicAdd(out, local * (1.f / B_ROWS));
}

extern "C" void kernel_launch(void* const* d_in, const int* in_sizes, int n_in,
                              void* d_out, int out_size, void* d_ws, size_t ws_size,
                              hipStream_t stream) {
  const float* features = (const float*)d_in[0];  // [16384,2048]
  const float* w1 = (const float*)d_in[1];        // [2048,2048]
  const float* b1 = (const float*)d_in[2];        // [2048]
  const float* w2 = (const float*)d_in[3];        // [2048,128]
  const float* b2 = (const float*)d_in[4];        // [128]
  float* out = (float*)d_out;                     // [1 + 16384*128]

  char* ws = (char*)d_ws;
  size_t off = 0;
  __bf16* A1  = (__bf16*)(ws + off); off += (size_t)B_ROWS * D_DIM * 2;  // 64 MB
  __bf16* h   = (__bf16*)(ws + off); off += (size_t)B_ROWS * H_DIM * 2;  // 64 MB
  __bf16* w1t = (__bf16*)(ws + off); off += (size_t)H_DIM * D_DIM * 2;   // 8 MB
  __bf16* w2t = (__bf16*)(ws + off); off += (size_t)F_DIM * H_DIM * 2;   // 512 KB
  __bf16* zbb = (__bf16*)(ws + off); off += (size_t)B_ROWS * F_DIM * 2;  // 4 MB
  float*  S   = (float*)(ws + off);  off += (size_t)B_ROWS * 4;          // 64 KB
  // column partials reuse the A1 region (dead after gemm1): 128*128*2*128 f32 = 16.8 MB
  float* colpart = (float*)A1;

  hipMemsetAsync(S, 0, (size_t)B_ROWS * 4, stream);
  hipMemsetAsync(out, 0, 4, stream);

  // convert features to bf16
  {
    int n = B_ROWS * D_DIM;
    cvt_bf16_kernel<<<n / (256 * 8), 256, 0, stream>>>(features, A1, n);
  }
  // transpose+convert W1 -> [H][D], W2 -> [F][H]
  transpose_cvt_kernel<<<dim3(H_DIM / 32, D_DIM / 32), dim3(32, 8), 0, stream>>>(w1, w1t, D_DIM, H_DIM);
  transpose_cvt_kernel<<<dim3(F_DIM / 32, H_DIM / 32), dim3(32, 8), 0, stream>>>(w2, w2t, H_DIM, F_DIM);

  // h = relu(features @ w1 + b1): 256x256 8-phase, single dispatch, 512 blocks
  gemm1_8ph_kernel<<<dim3((B_ROWS / 256) * (H_DIM / 256)), 512, 0, stream>>>(A1, w1t, b1, h);

  // z = normalize(h @ w2 + b2): f32 into d_out+1, bf16 copy for sim
  proj_norm_kernel<<<B_ROWS / 64, 256, 0, stream>>>(h, w2t, b2, out + 1, zbb, H_DIM);

  // S[i] = sum_{j != i} exp(sim_ij - 1/T), upper-triangle symmetric
  sim_lse_tri_kernel<<<1032, 256, 0, stream>>>(zbb, S, colpart);
  col_reduce_kernel<<<dim3(4, 128), 128, 0, stream>>>(colpart, S);

  // loss = mean(log(S)+1/T - pos)
  loss_kernel<<<B_ROWS / 64, 256, 0, stream>>>(out + 1, S, out);
}

// Round 6
// 482.321 us; speedup vs baseline: 1.0121x; 1.0121x over previous
//
#include <hip/hip_runtime.h>

typedef __attribute__((ext_vector_type(8))) __bf16 bf16x8;
typedef __attribute__((ext_vector_type(4))) float f32x4;

#define B_ROWS 16384
#define N_HALF 8192
#define D_DIM  2048
#define H_DIM  2048
#define F_DIM  128

static constexpr float kInvT = 14.285714285714286f;  // 1/0.07
static constexpr float kS2   = 20.60992915555662f;   // (1/0.07)*log2(e)

// async global->LDS, 16B per lane. LDS dest is wave-uniform base; HW adds lane*16.
__device__ __forceinline__ void async16(void* lds, const void* g) {
  __builtin_amdgcn_global_load_lds((const __attribute__((address_space(1))) void*)g,
                                   (__attribute__((address_space(3))) void*)lds,
                                   16, 0, 0);
}

// ---------------- f32 -> bf16 convert, 8 elems/thread ----------------
__global__ void cvt_bf16_kernel(const float* __restrict__ in, __bf16* __restrict__ out, int n) {
  int i = (blockIdx.x * blockDim.x + threadIdx.x) * 8;
  if (i >= n) return;
  float4 a = *(const float4*)(in + i);
  float4 b = *(const float4*)(in + i + 4);
  bf16x8 o;
  o[0] = (__bf16)a.x; o[1] = (__bf16)a.y; o[2] = (__bf16)a.z; o[3] = (__bf16)a.w;
  o[4] = (__bf16)b.x; o[5] = (__bf16)b.y; o[6] = (__bf16)b.z; o[7] = (__bf16)b.w;
  *(bf16x8*)(out + i) = o;
}

// ---------------- transpose + cvt: out[c][r] = in[r][c], block (32,8) ----------------
__global__ void transpose_cvt_kernel(const float* __restrict__ in, __bf16* __restrict__ out,
                                     int R, int C) {
  __shared__ float tile[32][33];
  int tx = threadIdx.x, ty = threadIdx.y;
  int c0 = blockIdx.x * 32, r0 = blockIdx.y * 32;
  for (int i = 0; i < 4; i++)
    tile[ty + i * 8][tx] = in[(size_t)(r0 + ty + i * 8) * C + c0 + tx];
  __syncthreads();
  for (int i = 0; i < 4; i++)
    out[(size_t)(c0 + ty + i * 8) * R + r0 + tx] = (__bf16)tile[tx][ty + i * 8];
}

// ---------------- GEMM1: 256x256 8-phase counted-vmcnt schedule ----------------
#define BM 256
#define BK 64
#define NT_K (D_DIM / BK)

__global__ __launch_bounds__(512, 2) void gemm1_8ph_kernel(
    const __bf16* __restrict__ A, const __bf16* __restrict__ BT,
    const float* __restrict__ bias, __bf16* __restrict__ C) {
  __shared__ __align__(16) __bf16 As[2][BM * BK];
  __shared__ __align__(16) __bf16 Bs[2][BM * BK];
  const int t = threadIdx.x;
  const int wave = t >> 6, lane = t & 63;
  const int l15 = lane & 15, quad = lane >> 4, l7 = l15 & 7;
  const int wy = wave & 1, wx = wave >> 1;  // 2M x 4N

  // XCD-bijective swizzle: 512 blocks, 8 XCDs, 64 per XCD.
  const int wg = ((int)blockIdx.x & 7) * 64 + ((int)blockIdx.x >> 3);
  const int n0 = (wg & 7) * 256;
  const int m0 = (wg >> 3) * 256;

  const int tr = t >> 3;
  const int csw = ((t & 7) ^ (tr & 7)) * 8;
  const __bf16* pA = A + (size_t)(m0 + tr) * D_DIM + csw;
  const __bf16* pB = BT + (size_t)(n0 + tr) * D_DIM + csw;
  const int ldsw = wave * 512;

  auto stageA = [&](int buf, int h, int kk) {
    async16(&As[buf][h * 8192 + ldsw], pA + (size_t)(h * 128) * D_DIM + kk);
    async16(&As[buf][h * 8192 + 4096 + ldsw], pA + (size_t)(h * 128 + 64) * D_DIM + kk);
  };
  auto stageB = [&](int buf, int h, int kk) {
    async16(&Bs[buf][h * 8192 + ldsw], pB + (size_t)(h * 128) * D_DIM + kk);
    async16(&Bs[buf][h * 8192 + 4096 + ldsw], pB + (size_t)(h * 128 + 64) * D_DIM + kk);
  };

  const int arow = wy * 16 + l15;
  const int brow = wx * 16 + l15;
  const int s0 = (quad ^ l7) * 8;
  const int s1 = ((4 + quad) ^ l7) * 8;

  f32x4 acc[8][4];
#pragma unroll
  for (int f = 0; f < 8; f++)
#pragma unroll
    for (int n = 0; n < 4; n++) acc[f][n] = 0.f;

  // prologue: t0.B, t0.A, t1.B (12 loads); wait until t0 fully landed.
  stageB(0, 0, 0); stageB(0, 1, 0);
  stageA(0, 0, 0); stageA(0, 1, 0);
  stageB(1, 0, BK); stageB(1, 1, BK);
  asm volatile("s_waitcnt vmcnt(4)" ::: "memory");
  __builtin_amdgcn_s_barrier();

  for (int tk = 0; tk < NT_K; ++tk) {
    const int cur = tk & 1, nxt = cur ^ 1;
    const __bf16* Ac = &As[cur][0];
    const __bf16* Bc = &Bs[cur][0];
#define LDA(f, s) (*(const bf16x8*)(Ac + ((f) * 32 + arow) * 64 + (s)))
#define LDB(n, s) (*(const bf16x8*)(Bc + ((n) * 64 + brow) * 64 + (s)))
    bf16x8 b0[4], b1[4];
    // ---- ph1: lo-frags x ks0 ; stage (t+1).Ah0 -> nxt ----
    {
      bf16x8 a0 = LDA(0, s0), a1 = LDA(1, s0), a2 = LDA(2, s0), a3 = LDA(3, s0);
      b0[0] = LDB(0, s0); b0[1] = LDB(1, s0); b0[2] = LDB(2, s0); b0[3] = LDB(3, s0);
      if (tk + 1 < NT_K) stageA(nxt, 0, (tk + 1) * BK);
      __builtin_amdgcn_s_barrier();
      asm volatile("s_waitcnt lgkmcnt(0)" ::: "memory");
      __builtin_amdgcn_s_setprio(1);
#pragma unroll
      for (int n = 0; n < 4; n++) {
        acc[0][n] = __builtin_amdgcn_mfma_f32_16x16x32_bf16(a0, b0[n], acc[0][n], 0, 0, 0);
        acc[1][n] = __builtin_amdgcn_mfma_f32_16x16x32_bf16(a1, b0[n], acc[1][n], 0, 0, 0);
        acc[2][n] = __builtin_amdgcn_mfma_f32_16x16x32_bf16(a2, b0[n], acc[2][n], 0, 0, 0);
        acc[3][n] = __builtin_amdgcn_mfma_f32_16x16x32_bf16(a3, b0[n], acc[3][n], 0, 0, 0);
      }
      __builtin_amdgcn_s_setprio(0);
      __builtin_amdgcn_s_barrier();
    }
    // ---- ph2: hi-frags x ks0 ; stage (t+1).Ah1 -> nxt ----
    {
      bf16x8 a4 = LDA(4, s0), a5 = LDA(5, s0), a6 = LDA(6, s0), a7 = LDA(7, s0);
      if (tk + 1 < NT_K) stageA(nxt, 1, (tk + 1) * BK);
      __builtin_amdgcn_s_barrier();
      asm volatile("s_waitcnt lgkmcnt(0)" ::: "memory");
      __builtin_amdgcn_s_setprio(1);
#pragma unroll
      for (int n = 0; n < 4; n++) {
        acc[4][n] = __builtin_amdgcn_mfma_f32_16x16x32_bf16(a4, b0[n], acc[4][n], 0, 0, 0);
        acc[5][n] = __builtin_amdgcn_mfma_f32_16x16x32_bf16(a5, b0[n], acc[5][n], 0, 0, 0);
        acc[6][n] = __builtin_amdgcn_mfma_f32_16x16x32_bf16(a6, b0[n], acc[6][n], 0, 0, 0);
        acc[7][n] = __builtin_amdgcn_mfma_f32_16x16x32_bf16(a7, b0[n], acc[7][n], 0, 0, 0);
      }
      __builtin_amdgcn_s_setprio(0);
      __builtin_amdgcn_s_barrier();
    }
    // ---- ph3: lo-frags x ks1 ; no stage ----
    {
      bf16x8 a0 = LDA(0, s1), a1 = LDA(1, s1), a2 = LDA(2, s1), a3 = LDA(3, s1);
      b1[0] = LDB(0, s1); b1[1] = LDB(1, s1); b1[2] = LDB(2, s1); b1[3] = LDB(3, s1);
      __builtin_amdgcn_s_barrier();
      asm volatile("s_waitcnt lgkmcnt(0)" ::: "memory");
      __builtin_amdgcn_s_setprio(1);
#pragma unroll
      for (int n = 0; n < 4; n++) {
        acc[0][n] = __builtin_amdgcn_mfma_f32_16x16x32_bf16(a0, b1[n], acc[0][n], 0, 0, 0);
        acc[1][n] = __builtin_amdgcn_mfma_f32_16x16x32_bf16(a1, b1[n], acc[1][n], 0, 0, 0);
        acc[2][n] = __builtin_amdgcn_mfma_f32_16x16x32_bf16(a2, b1[n], acc[2][n], 0, 0, 0);
        acc[3][n] = __builtin_amdgcn_mfma_f32_16x16x32_bf16(a3, b1[n], acc[3][n], 0, 0, 0);
      }
      __builtin_amdgcn_s_setprio(0);
      __builtin_amdgcn_s_barrier();
    }
    // ---- ph4: hi-frags x ks1 ; stage (t+2).B -> cur ; vmcnt AFTER MFMA (R6) ----
    {
      bf16x8 a4 = LDA(4, s1), a5 = LDA(5, s1), a6 = LDA(6, s1), a7 = LDA(7, s1);
      const bool st = (tk + 2 < NT_K);
      if (st) {
        stageB(cur, 0, (tk + 2) * BK);
        stageB(cur, 1, (tk + 2) * BK);
      }
      __builtin_amdgcn_s_barrier();
      asm volatile("s_waitcnt lgkmcnt(0)" ::: "memory");
      __builtin_amdgcn_s_setprio(1);
#pragma unroll
      for (int n = 0; n < 4; n++) {
        acc[4][n] = __builtin_amdgcn_mfma_f32_16x16x32_bf16(a4, b1[n], acc[4][n], 0, 0, 0);
        acc[5][n] = __builtin_amdgcn_mfma_f32_16x16x32_bf16(a5, b1[n], acc[5][n], 0, 0, 0);
        acc[6][n] = __builtin_amdgcn_mfma_f32_16x16x32_bf16(a6, b1[n], acc[6][n], 0, 0, 0);
        acc[7][n] = __builtin_amdgcn_mfma_f32_16x16x32_bf16(a7, b1[n], acc[7][n], 0, 0, 0);
      }
      __builtin_amdgcn_s_setprio(0);
      // drain A(t+1) (and old B) only here -- MFMA block above covers more latency
      if (st) {
        asm volatile("s_waitcnt vmcnt(4)" ::: "memory");
      } else if (tk + 1 < NT_K) {
        asm volatile("s_waitcnt vmcnt(0)" ::: "memory");
      }
      __builtin_amdgcn_s_barrier();
    }
#undef LDA
#undef LDB
  }

  // epilogue: bias + relu, bf16 store
#pragma unroll
  for (int n = 0; n < 4; n++) {
    int col = n0 + n * 64 + wx * 16 + l15;
    float bv = bias[col];
#pragma unroll
    for (int f = 0; f < 8; f++) {
      int rowb = m0 + f * 32 + wy * 16 + quad * 4;
#pragma unroll
      for (int r = 0; r < 4; r++) {
        float v = fmaxf(acc[f][n][r] + bv, 0.f);
        C[(size_t)(rowb + r) * H_DIM + col] = (__bf16)v;
      }
    }
  }
}

// ---------------- fused GEMM2 + bias + L2-normalize: z = norm(A @ BT^T + b2) ----------------
// R6: depth-4 counted-vmcnt pipeline, 5 LDS buffers, ONE barrier per K-iter.
// Stage k+4 goes into buffer (k+4)%5, last read at iter k-1 (dead past its
// barrier). Steady-state vmcnt(9): k+1 drained, k+2..k+4 (9 loads) in flight
// -- ~3 iterations (~1200 cy) of HBM-latency cover. Tail: 6/3/0.
__global__ __launch_bounds__(256) void proj_norm_kernel(
    const __bf16* __restrict__ A, const __bf16* __restrict__ BT,
    const float* __restrict__ bias, float* __restrict__ zf, __bf16* __restrict__ zb, int K) {
  __shared__ __align__(16) __bf16 As[5 * 64 * 32];
  __shared__ __align__(16) __bf16 Bs[5 * 128 * 32];
  __shared__ float pbuf[64 * 128];
  const int t = threadIdx.x;
  const int wave = t >> 6, lane = t & 63;
  const int l15 = lane & 15, quad = lane >> 4;
  const int wy = wave >> 1, wx = wave & 1;
  const int m0 = blockIdx.x * 64;
  const int sr = t >> 2;
  const int sk = (((t & 3) ^ ((sr >> 1) & 3))) * 8;
  const int sw = (l15 >> 1) & 3;
  const int NK = K / 32;  // 64

  auto stage = [&](int buf, int k0) {
    async16(As + buf * 2048 + wave * 512, A + (size_t)(m0 + sr) * K + k0 + sk);
    async16(Bs + buf * 4096 + wave * 512, BT + (size_t)(0  + sr) * K + k0 + sk);
    async16(Bs + buf * 4096 + 2048 + wave * 512, BT + (size_t)(64 + sr) * K + k0 + sk);
  };

  f32x4 acc[2][4];
  for (int i = 0; i < 2; i++)
    for (int j = 0; j < 4; j++) acc[i][j] = 0.f;

  // prologue: prefetch k=0..3, drain k0, keep 9 in flight
  stage(0, 0); stage(1, 32); stage(2, 64); stage(3, 96);
  asm volatile("s_waitcnt vmcnt(9)" ::: "memory");
  __builtin_amdgcn_s_barrier();

  for (int kk = 0; kk < NK; ++kk) {
    const int cur = kk % 5;
    bf16x8 af[2], bfr[4];
    for (int i = 0; i < 2; i++)
      af[i] = *(const bf16x8*)(As + cur * 2048 + (wy * 32 + i * 16 + l15) * 32 + (quad ^ sw) * 8);
    for (int i = 0; i < 4; i++)
      bfr[i] = *(const bf16x8*)(Bs + cur * 4096 + (wx * 64 + i * 16 + l15) * 32 + (quad ^ sw) * 8);
    if (kk + 4 < NK) stage((kk + 4) % 5, (kk + 4) * 32);
    asm volatile("s_waitcnt lgkmcnt(0)" ::: "memory");  // my reads complete (protocol order vs barrier)
    if (kk + 4 < NK) {
      asm volatile("s_waitcnt vmcnt(9)" ::: "memory");  // k+1 landed
    } else if (kk == NK - 4) {
      asm volatile("s_waitcnt vmcnt(6)" ::: "memory");
    } else if (kk == NK - 3) {
      asm volatile("s_waitcnt vmcnt(3)" ::: "memory");
    } else {
      asm volatile("s_waitcnt vmcnt(0)" ::: "memory");
    }
    __builtin_amdgcn_s_barrier();
    for (int mi = 0; mi < 2; mi++)
      for (int ni = 0; ni < 4; ni++)
        acc[mi][ni] = __builtin_amdgcn_mfma_f32_16x16x32_bf16(af[mi], bfr[ni], acc[mi][ni], 0, 0, 0);
  }
  __syncthreads();
  // epilogue: p + bias into LDS
  for (int ni = 0; ni < 4; ni++) {
    int col = wx * 64 + ni * 16 + l15;
    float bv = bias[col];
    for (int mi = 0; mi < 2; mi++) {
      int lrow = wy * 32 + mi * 16 + quad * 4;
      for (int r = 0; r < 4; r++)
        pbuf[(lrow + r) * 128 + col] = acc[mi][ni][r] + bv;
    }
  }
  __syncthreads();
  // normalize: wave handles rows [wave*16, wave*16+16)
  for (int it = 0; it < 16; it++) {
    int lrow = wave * 16 + it;
    float v0 = pbuf[lrow * 128 + lane];
    float v1 = pbuf[lrow * 128 + 64 + lane];
    float ss = v0 * v0 + v1 * v1;
    for (int m = 1; m < 64; m <<= 1) ss += __shfl_xor(ss, m);
    float inv = 1.f / fmaxf(sqrtf(ss), 1e-12f);
    float z0 = v0 * inv, z1 = v1 * inv;
    size_t base = (size_t)(m0 + lrow) * F_DIM;
    zf[base + lane] = z0;
    zf[base + 64 + lane] = z1;
    zb[base + lane] = (__bf16)z0;
    zb[base + 64 + lane] = (__bf16)z1;
  }
}

// ---------------- sim + row-sum of exp, SYMMETRIC upper-triangle version ----------------
// R6: grid = 1024 blocks EXACTLY (4 blocks/CU x 256 CU = full residency, no
// straggler round -- 1032 blocks left 8 stragglers serializing a whole block
// duration, which masked the 2x work reduction in R3/R5). Block b owns tiles
// [b*8256/1024, (b+1)*8256/1024) -> 8 or 9 tiles, makespan ~= mean*1.12.
__global__ __launch_bounds__(256) void sim_lse_tri_kernel(const __bf16* __restrict__ zb,
                                                          float* __restrict__ S,
                                                          float* __restrict__ colpart) {
  __shared__ __align__(16) __bf16 Bs[128 * 128];
  const int t = threadIdx.x;
  const int wave = t >> 6, lane = t & 63;
  const int l15 = lane & 15, quad = lane >> 4;
  const int wy = wave >> 1, wx = wave & 1;
  const int srow = t >> 4;
  const int schunk = (t & 15) ^ srow;

  const int u0 = (int)(((long)blockIdx.x * 8256) >> 10);
  const int u1 = (int)(((long)(blockIdx.x + 1) * 8256) >> 10);

  auto fr = [](int r) { return r * 128 - (r * (r - 1)) / 2; };
  int rt = (int)(128.5f - sqrtf(16512.25f - 2.0f * (float)u0));
  while (fr(rt + 1) <= u0) rt++;
  while (fr(rt) > u0) rt--;
  int ct = rt + (u0 - fr(rt));

  bf16x8 a[4][4];
  float rowacc[4][4];
  auto load_a = [&](int rtile) {
#pragma unroll
    for (int mi = 0; mi < 4; mi++)
#pragma unroll
      for (int ks = 0; ks < 4; ks++)
        a[mi][ks] = *(const bf16x8*)(zb + (size_t)(rtile * 128 + wy * 64 + mi * 16 + l15) * 128 +
                                     ks * 32 + quad * 8);
  };
  auto flush_rows = [&](int rtile) {
#pragma unroll
    for (int mi = 0; mi < 4; mi++)
#pragma unroll
      for (int r = 0; r < 4; r++) {
        float v = rowacc[mi][r];
        v += __shfl_xor(v, 1);
        v += __shfl_xor(v, 2);
        v += __shfl_xor(v, 4);
        v += __shfl_xor(v, 8);
        if (l15 == 0)
          atomicAdd(&S[rtile * 128 + wy * 64 + mi * 16 + quad * 4 + r], v);
        rowacc[mi][r] = 0.f;
      }
  };

#pragma unroll
  for (int mi = 0; mi < 4; mi++)
#pragma unroll
    for (int r = 0; r < 4; r++) rowacc[mi][r] = 0.f;
  load_a(rt);

  for (int u = u0; u < u1; ++u) {
    // stage B tile (rows ct*128..+128 of zb), 16-chunk XOR swizzle
    const __bf16* gbase = zb + (size_t)(ct * 128) * 128;
#pragma unroll
    for (int q = 0; q < 8; q++)
      async16(Bs + q * 2048 + wave * 512, gbase + (size_t)(q * 16 + srow) * 128 + schunk * 8);
    __syncthreads();
    const bool diag = (ct == rt);  // block-uniform
#pragma unroll
    for (int ni = 0; ni < 4; ni++) {
      bf16x8 b[4];
      const int brow = wx * 64 + ni * 16 + l15;
#pragma unroll
      for (int ks = 0; ks < 4; ks++)
        b[ks] = *(const bf16x8*)(Bs + brow * 128 + (((ks * 4 + quad) ^ l15) * 8));
      float colsum = 0.f;
      if (diag) {
#pragma unroll
        for (int mi = 0; mi < 4; mi++) {
          f32x4 acc = 0.f;
#pragma unroll
          for (int ks = 0; ks < 4; ks++)
            acc = __builtin_amdgcn_mfma_f32_16x16x32_bf16(a[mi][ks], b[ks], acc, 0, 0, 0);
          const int lrb = wy * 64 + mi * 16 + quad * 4;
#pragma unroll
          for (int r = 0; r < 4; r++) {
            float term = __builtin_amdgcn_exp2f(fmaf(acc[r], kS2, -kS2));
            rowacc[mi][r] += (lrb + r == brow) ? 0.f : term;
          }
        }
      } else {
#pragma unroll
        for (int mi = 0; mi < 4; mi++) {
          f32x4 acc = 0.f;
#pragma unroll
          for (int ks = 0; ks < 4; ks++)
            acc = __builtin_amdgcn_mfma_f32_16x16x32_bf16(a[mi][ks], b[ks], acc, 0, 0, 0);
#pragma unroll
          for (int r = 0; r < 4; r++) {
            float term = __builtin_amdgcn_exp2f(fmaf(acc[r], kS2, -kS2));
            rowacc[mi][r] += term;
            colsum += term;
          }
        }
        // column partials: reduce over quads, then plain store (no atomics)
        colsum += __shfl_xor(colsum, 16);
        colsum += __shfl_xor(colsum, 32);
        if (quad == 0)
          colpart[((size_t)(ct * 128 + rt) * 2 + wy) * 128 + brow] = colsum;
      }
    }
    __syncthreads();
    if (u + 1 < u1) {
      ct++;
      if (ct == 128) {
        flush_rows(rt);
        rt++;
        ct = rt;
        load_a(rt);
      }
    }
  }
  flush_rows(rt);
}

// ---------------- fold column partials into S ----------------
// grid (4 rt-chunks, 128 ct), 128 threads (one per col). <=4 atomics/address.
__global__ __launch_bounds__(128) void col_reduce_kernel(const float* __restrict__ colpart,
                                                         float* __restrict__ S) {
  const int ct = blockIdx.y;
  const int r0 = blockIdx.x * 32;
  if (r0 >= ct) return;
  const int t = threadIdx.x;
  const int rend = min(ct, r0 + 32);
  float s = 0.f;
  for (int rt = r0; rt < rend; rt++) {
    const float* p = colpart + (size_t)(ct * 128 + rt) * 2 * 128;
    s += p[t] + p[128 + t];
  }
  atomicAdd(&S[ct * 128 + t], s);
}

// ---------------- pos + loss reduction ----------------
__global__ void loss_kernel(const float* __restrict__ zf, const float* __restrict__ S,
                            float* __restrict__ out) {
  int wave = threadIdx.x >> 6, lane = threadIdx.x & 63;
  int base = blockIdx.x * 64 + wave * 16;
  float local = 0.f;
  for (int it = 0; it < 16; it++) {
    int row = base + it;
    int j = (row + N_HALF) & (B_ROWS - 1);
    const float* za = zf + (size_t)row * F_DIM;
    const float* zc = zf + (size_t)j * F_DIM;
    float d = za[lane] * zc[lane] + za[lane + 64] * zc[lane + 64];
    for (int m = 1; m < 64; m <<= 1) d += __shfl_xor(d, m);
    float pos = d * kInvT;
    float lse = logf(S[row]) + kInvT;
    local += (lse - pos);
  }
  if (lane == 0) atomicAdd(out, local * (1.f / B_ROWS));
}

extern "C" void kernel_launch(void* const* d_in, const int* in_sizes, int n_in,
                              void* d_out, int out_size, void* d_ws, size_t ws_size,
                              hipStream_t stream) {
  const float* features = (const float*)d_in[0];  // [16384,2048]
  const float* w1 = (const float*)d_in[1];        // [2048,2048]
  const float* b1 = (const float*)d_in[2];        // [2048]
  const float* w2 = (const float*)d_in[3];        // [2048,128]
  const float* b2 = (const float*)d_in[4];        // [128]
  float* out = (float*)d_out;                     // [1 + 16384*128]

  char* ws = (char*)d_ws;
  size_t off = 0;
  __bf16* A1  = (__bf16*)(ws + off); off += (size_t)B_ROWS * D_DIM * 2;  // 64 MB
  __bf16* h   = (__bf16*)(ws + off); off += (size_t)B_ROWS * H_DIM * 2;  // 64 MB
  __bf16* w1t = (__bf16*)(ws + off); off += (size_t)H_DIM * D_DIM * 2;   // 8 MB
  __bf16* w2t = (__bf16*)(ws + off); off += (size_t)F_DIM * H_DIM * 2;   // 512 KB
  __bf16* zbb = (__bf16*)(ws + off); off += (size_t)B_ROWS * F_DIM * 2;  // 4 MB
  float*  S   = (float*)(ws + off);  off += (size_t)B_ROWS * 4;          // 64 KB
  // column partials reuse the A1 region (dead after gemm1): 128*128*2*128 f32 = 16.8 MB
  float* colpart = (float*)A1;

  hipMemsetAsync(S, 0, (size_t)B_ROWS * 4, stream);
  hipMemsetAsync(out, 0, 4, stream);

  // convert features to bf16
  {
    int n = B_ROWS * D_DIM;
    cvt_bf16_kernel<<<n / (256 * 8), 256, 0, stream>>>(features, A1, n);
  }
  // transpose+convert W1 -> [H][D], W2 -> [F][H]
  transpose_cvt_kernel<<<dim3(H_DIM / 32, D_DIM / 32), dim3(32, 8), 0, stream>>>(w1, w1t, D_DIM, H_DIM);
  transpose_cvt_kernel<<<dim3(F_DIM / 32, H_DIM / 32), dim3(32, 8), 0, stream>>>(w2, w2t, H_DIM, F_DIM);

  // h = relu(features @ w1 + b1): 256x256 8-phase, single dispatch, 512 blocks
  gemm1_8ph_kernel<<<dim3((B_ROWS / 256) * (H_DIM / 256)), 512, 0, stream>>>(A1, w1t, b1, h);

  // z = normalize(h @ w2 + b2): f32 into d_out+1, bf16 copy for sim
  proj_norm_kernel<<<B_ROWS / 64, 256, 0, stream>>>(h, w2t, b2, out + 1, zbb, H_DIM);

  // S[i] = sum_{j != i} exp(sim_ij - 1/T), upper-triangle symmetric, balanced 1024 blocks
  sim_lse_tri_kernel<<<1024, 256, 0, stream>>>(zbb, S, colpart);
  col_reduce_kernel<<<dim3(4, 128), 128, 0, stream>>>(colpart, S);

  // loss = mean(log(S)+1/T - pos)
  loss_kernel<<<B_ROWS / 64, 256, 0, stream>>>(out + 1, S, out);
}